// Round 1
// baseline (3924.000 us; speedup 1.0000x reference)
//
#include <hip/hip_runtime.h>

// Neurcomp / SIREN MLP inference, fp32 VALU baseline.
// One point per thread. h[128] register-resident; z2 accumulator split
// 64 VGPR / 64 LDS (per-thread private slots -> no barriers, no conflicts).
// Weights accessed with wave-uniform indices -> scalar (s_load) path.

constexpr float OMEGA = 30.0f;
constexpr int HID  = 128;
constexpr int NRES = 7;
constexpr int JC   = 8;            // s1 chunk per kc iteration
constexpr int NKC  = HID / JC;     // 16
constexpr int BT   = 256;          // threads per block
constexpr int ZREG = 64;           // z2 entries in registers
constexpr int ZLDS = HID - ZREG;   // z2 entries in LDS (64)

__device__ __forceinline__ float sin_om(float z) {
    // sin(OMEGA * z): convert to revolutions, fract, hardware v_sin_f32
    float r = z * (OMEGA * 0.15915494309189535f);
    r = r - floorf(r);
    return __builtin_amdgcn_sinf(r);
}

__global__ __launch_bounds__(BT, 2) void siren_kernel(
    const float* __restrict__ x,
    const float* __restrict__ w0, const float* __restrict__ b0,
    const float* __restrict__ rw1, const float* __restrict__ rb1,
    const float* __restrict__ rw2, const float* __restrict__ rb2,
    const float* __restrict__ wf, const float* __restrict__ bf,
    float* __restrict__ out, int n)
{
    // [o-pair][2*tid + (0|1)]: lane-consecutive -> conflict-free, 64 KB
    __shared__ float z2s[ZLDS / 2][2 * BT];

    const int tid = threadIdx.x;
    const int gid = blockIdx.x * BT + tid;
    const int idx = (gid < n) ? gid : (n - 1);   // clamp; store is guarded

    const float x0 = x[3 * idx + 0];
    const float x1 = x[3 * idx + 1];
    const float x2 = x[3 * idx + 2];

    float H[HID];
#pragma unroll
    for (int o = 0; o < HID; ++o) {
        float z = fmaf(w0[3 * o + 0], x0,
                  fmaf(w0[3 * o + 1], x1,
                  fmaf(w0[3 * o + 2], x2, b0[o])));
        H[o] = sin_om(z);
    }

    for (int i = 0; i < NRES; ++i) {
        const float wgt1 = (i > 0) ? 0.5f : 1.0f;           // ave_first
        const float wgt2 = (i == NRES - 1) ? 0.5f : 1.0f;   // ave_second
        const float* __restrict__ W1 = rw1 + i * HID * HID;
        const float* __restrict__ W2 = rw2 + i * HID * HID;
        const float* __restrict__ B1 = rb1 + i * HID;
        const float* __restrict__ B2 = rb2 + i * HID;

        float z2r[ZREG];
#pragma unroll
        for (int o = 0; o < ZREG; ++o) z2r[o] = B2[o];
#pragma unroll
        for (int p = 0; p < ZLDS / 2; ++p) {
            z2s[p][2 * tid + 0] = B2[ZREG + 2 * p + 0];
            z2s[p][2 * tid + 1] = B2[ZREG + 2 * p + 1];
        }

        for (int kc = 0; kc < NKC; ++kc) {
            // ---- matmul 1: sc[j] = sin(30*(wgt1 * <w1[k'], H> + b1[k']))
            float sc[JC];
#pragma unroll
            for (int j = 0; j < JC; ++j) {
                const float* __restrict__ w1r = W1 + (kc * JC + j) * HID;
                float a0 = 0.f, a1 = 0.f, a2 = 0.f, a3 = 0.f;
#pragma unroll
                for (int k = 0; k < HID; k += 4) {
                    a0 = fmaf(w1r[k + 0], H[k + 0], a0);
                    a1 = fmaf(w1r[k + 1], H[k + 1], a1);
                    a2 = fmaf(w1r[k + 2], H[k + 2], a2);
                    a3 = fmaf(w1r[k + 3], H[k + 3], a3);
                }
                sc[j] = sin_om(fmaf(wgt1, (a0 + a1) + (a2 + a3),
                                    B1[kc * JC + j]));
            }
            // ---- matmul 2 (rank-JC update), register half
#pragma unroll
            for (int o = 0; o < ZREG; ++o) {
                const float* __restrict__ w2r = W2 + o * HID + kc * JC;
                float t = z2r[o];
#pragma unroll
                for (int j = 0; j < JC; ++j) t = fmaf(w2r[j], sc[j], t);
                z2r[o] = t;
            }
            // ---- matmul 2, LDS half (private slots, b64 accesses)
#pragma unroll
            for (int p = 0; p < ZLDS / 2; ++p) {
                const int o = ZREG + 2 * p;
                float2 v = *reinterpret_cast<float2*>(&z2s[p][2 * tid]);
                const float* __restrict__ wa = W2 + (o + 0) * HID + kc * JC;
                const float* __restrict__ wb = W2 + (o + 1) * HID + kc * JC;
#pragma unroll
                for (int j = 0; j < JC; ++j) {
                    v.x = fmaf(wa[j], sc[j], v.x);
                    v.y = fmaf(wb[j], sc[j], v.y);
                }
                *reinterpret_cast<float2*>(&z2s[p][2 * tid]) = v;
            }
        }

        // ---- epilogue: H = wgt2 * (H + sin(30*(z2 + b2)))  (b2 pre-folded)
#pragma unroll
        for (int o = 0; o < ZREG; ++o)
            H[o] = wgt2 * (H[o] + sin_om(z2r[o]));
#pragma unroll
        for (int p = 0; p < ZLDS / 2; ++p) {
            float2 v = *reinterpret_cast<float2*>(&z2s[p][2 * tid]);
            H[ZREG + 2 * p + 0] = wgt2 * (H[ZREG + 2 * p + 0] + sin_om(v.x));
            H[ZREG + 2 * p + 1] = wgt2 * (H[ZREG + 2 * p + 1] + sin_om(v.y));
        }
    }

    // ---- final linear head
    float acc = bf[0];
#pragma unroll
    for (int k = 0; k < HID; k += 4) {
        acc = fmaf(wf[k + 0], H[k + 0], acc);
        acc = fmaf(wf[k + 1], H[k + 1], acc);
        acc = fmaf(wf[k + 2], H[k + 2], acc);
        acc = fmaf(wf[k + 3], H[k + 3], acc);
    }
    if (gid < n) out[gid] = acc;
}

extern "C" void kernel_launch(void* const* d_in, const int* in_sizes, int n_in,
                              void* d_out, int out_size, void* d_ws, size_t ws_size,
                              hipStream_t stream) {
    const float* x   = (const float*)d_in[0];
    const float* w0  = (const float*)d_in[1];
    const float* b0  = (const float*)d_in[2];
    const float* rw1 = (const float*)d_in[3];
    const float* rb1 = (const float*)d_in[4];
    const float* rw2 = (const float*)d_in[5];
    const float* rb2 = (const float*)d_in[6];
    const float* wf  = (const float*)d_in[7];
    const float* bf  = (const float*)d_in[8];
    float* out = (float*)d_out;

    const int n = in_sizes[0] / 3;   // 200000
    const int grid = (n + BT - 1) / BT;
    siren_kernel<<<grid, BT, 0, stream>>>(x, w0, b0, rw1, rb1, rw2, rb2,
                                          wf, bf, out, n);
}